// Round 7
// baseline (140.600 us; speedup 1.0000x reference)
//
#include <hip/hip_runtime.h>

// ---------------------------------------------------------------------------
// Sparse3DNA: x->QKV proj (bf16 MFMA GEMM), 3x3x3 causal window attention
// (+BOS), output proj. Shapes: b=2, T=4096 (4x32x32), DIM=512, 8 heads x 64.
// R7: attn v3 — packed bf16 pair conversion (2 VALU / 2 elems), 4-way split
// dot accumulators, and V-row prefetch issued BEFORE the softmax shfl chain
// (vmcnt FIFO: Q/K loads first, V after, so dot's wait leaves V in flight).
// GEMM = R6 dbuf structure (raw s_barrier + s_waitcnt vmcnt(NLD)).
// ---------------------------------------------------------------------------

#define T_TOK   4096
#define DIM     512
#define NQKV    1536

typedef unsigned short u16;
typedef unsigned int   u32;
typedef unsigned long long u64;
typedef __attribute__((ext_vector_type(8))) short short8;   // 8 bf16 (4 VGPR)
typedef __attribute__((ext_vector_type(4))) float f32x4;

__device__ __forceinline__ u16 f2bf(float f) {           // RNE float->bf16
    u32 u = __float_as_uint(f);
    return (u16)((u + 0x7fffu + ((u >> 16) & 1u)) >> 16);
}
__device__ __forceinline__ float b2f(u16 u) {
    return __uint_as_float(((u32)u) << 16);
}
__device__ __forceinline__ float bflo(u32 u) {           // low bf16 of pair
    return __uint_as_float(u << 16);
}
__device__ __forceinline__ float bfhi(u32 u) {           // high bf16 of pair
    return __uint_as_float(u & 0xffff0000u);
}

__device__ __forceinline__ void gload_lds16(const void* g, void* l) {
    // async global->LDS, 16B/lane; LDS dest = wave-uniform base + lane*16
    __builtin_amdgcn_global_load_lds(
        (const __attribute__((address_space(1))) void*)g,
        (__attribute__((address_space(3))) void*)l, 16, 0, 0);
}

// ---------------------------------------------------------------------------
// merged cast kernel.
//  blocks [0,4096): x fp32 -> bf16 (vectorized)
//  blocks [4096,4288): Wt[n][k] = [Wq|Wk|Wv](k,n), LDS-tiled 64x64 transpose
//  blocks [4288,4352): Wot[n][k] = Wo[k][n], same
// ---------------------------------------------------------------------------
__global__ void cast_all_kernel(const float4* __restrict__ x,
                                const float* __restrict__ Wq, const float* __restrict__ Wkv,
                                const float* __restrict__ Wo,
                                u16* __restrict__ xb, u16* __restrict__ Wt,
                                u16* __restrict__ Wot) {
    __shared__ float S[64 * 65];
    int blk = blockIdx.x;
    int tid = threadIdx.x;
    if (blk < 4096) {
        int i = blk * 256 + tid;                  // 1,048,576 float4s
        float4 v = x[i];
        u64 pack = (u64)f2bf(v.x) | ((u64)f2bf(v.y) << 16) |
                   ((u64)f2bf(v.z) << 32) | ((u64)f2bf(v.w) << 48);
        ((u64*)xb)[i] = pack;
        return;
    }
    int isWo = blk >= 4288;
    int tIdx = isWo ? (blk - 4288) : (blk - 4096);
    int tn = tIdx >> 3, tk = tIdx & 7;            // n-tile, k-tile
    #pragma unroll
    for (int p = 0; p < 16; ++p) {                // stage, coalesced over n
        int kl = p * 4 + (tid >> 6), nl = tid & 63;
        int gk = tk * 64 + kl, gn = tn * 64 + nl;
        float v;
        if (isWo)            v = Wo[gk * 512 + gn];
        else if (gn < 512)   v = Wq[gk * 512 + gn];
        else                 v = Wkv[gk * 1024 + (gn - 512)];
        S[kl * 65 + nl] = v;
    }
    __syncthreads();
    u16* dst = isWo ? Wot : Wt;
    #pragma unroll
    for (int p = 0; p < 16; ++p) {                // write, coalesced over k
        int nl = p * 4 + (tid >> 6), kl = tid & 63;
        dst[(size_t)(tn * 64 + nl) * 512 + tk * 64 + kl] = f2bf(S[kl * 65 + nl]);
    }
}

// ---------------------------------------------------------------------------
// NT GEMM, double-buffered: C(MxN) = A(MxK) * B(NxK)^T, K=512, bf16, fp32 acc.
// BMxBN / block, 4 waves (2x2), wave tile (BM/2)x(BN/2), mfma 16x16x32, BK=32.
// LDS XOR-swizzle: slot(r,kc) = r*4 + ((kc + (r>>1)) & 3) -> ds_read_b128
// lands 2 lanes/bank (free, m136).  K-loop per step:
//   stage(ks+1 -> buf^1); s_waitcnt vmcnt(NLD); s_barrier; frags+MFMA;
//   s_waitcnt lgkmcnt(0); s_barrier.
// MODE 0: bf16 store. MODE 1: fp32 store + bias.
// ---------------------------------------------------------------------------
template <int BM, int BN, int MODE>
__global__ __launch_bounds__(256)
void gemm_nt(const u16* __restrict__ A, const u16* __restrict__ B,
             void* __restrict__ Cv, const float* __restrict__ bias,
             int lda, int ldb, int ldc) {
    constexpr int K = 512, BK = 32, KSTEPS = K / BK;
    constexpr int ACH = BM * 4;                  // A 16B-chunks per K-step
    constexpr int NCH = (BM + BN) * 4;
    constexpr int NLD = NCH / 256;               // chunks per thread per stage
    constexpr int ABYTES = BM * 64;
    constexpr int HALF = (BM + BN) * 64;         // one buffer
    constexpr int MI = BM / 32, NJ = BN / 32;
    __shared__ __align__(16) char lds[2 * HALF];
    const int tid  = threadIdx.x;
    const int lane = tid & 63, wave = tid >> 6;
    const int quad = lane >> 4, mrow = lane & 15;
    const int wm = wave >> 1, wn = wave & 1;
    const int bm = blockIdx.y, bn = blockIdx.x;

    const char* gptr[NLD];
    char*       lptr[NLD];
    #pragma unroll
    for (int it = 0; it < NLD; ++it) {
        int c   = it * 256 + tid;                // chunk id, lane-consecutive
        int inB = (c >= ACH);
        int a   = inB ? c - ACH : c;
        int r   = a >> 2;                        // tile row
        int kc  = ((a & 3) - (r >> 1)) & 3;      // inverse swizzle
        int row = (inB ? bn * BN : bm * BM) + r;
        const u16* base = inB ? B : A;
        int ld = inB ? ldb : lda;
        gptr[it] = (const char*)(base + (size_t)row * ld + kc * 8);
        lptr[it] = (char*)lds + (it * 256 + wave * 64) * 16;   // wave-uniform
    }
    const char* aLds[MI];
    const char* bLds[NJ];
    #pragma unroll
    for (int i = 0; i < MI; ++i) {
        int ra = wm * (BM / 2) + i * 16 + mrow;
        aLds[i] = lds + (ra * 4 + ((quad + (ra >> 1)) & 3)) * 16;
    }
    #pragma unroll
    for (int j = 0; j < NJ; ++j) {
        int rb = wn * (BN / 2) + j * 16 + mrow;
        bLds[j] = lds + ABYTES + (rb * 4 + ((quad + (rb >> 1)) & 3)) * 16;
    }

    f32x4 acc[MI][NJ] = {};
    #pragma unroll
    for (int it = 0; it < NLD; ++it)             // prologue: stage 0 -> buf 0
        gload_lds16(gptr[it], lptr[it]);

    #pragma unroll
    for (int ks = 0; ks < KSTEPS; ++ks) {
        const int cur = ks & 1;
        if (ks + 1 < KSTEPS) {                   // prefetch next stage
            #pragma unroll
            for (int it = 0; it < NLD; ++it)
                gload_lds16(gptr[it] + 2 * (ks + 1) * BK, lptr[it] + (cur ^ 1) * HALF);
            asm volatile("s_waitcnt vmcnt(%0)" :: "i"(NLD) : "memory");
        } else {
            asm volatile("s_waitcnt vmcnt(0)" ::: "memory");
        }
        asm volatile("s_barrier" ::: "memory");  // stage ks visible to all

        short8 af[MI], bf[NJ];
        #pragma unroll
        for (int i = 0; i < MI; ++i) af[i] = *(const short8*)(aLds[i] + cur * HALF);
        #pragma unroll
        for (int j = 0; j < NJ; ++j) bf[j] = *(const short8*)(bLds[j] + cur * HALF);
        #pragma unroll
        for (int i = 0; i < MI; ++i)
            #pragma unroll
            for (int j = 0; j < NJ; ++j)
                acc[i][j] = __builtin_amdgcn_mfma_f32_16x16x32_bf16(af[i], bf[j], acc[i][j], 0, 0, 0);
        asm volatile("s_waitcnt lgkmcnt(0)" ::: "memory");
        asm volatile("s_barrier" ::: "memory");  // all waves done reading buf
    }

    // epilogue: D row = quad*4 + reg, col = lane&15 (m89-verified layout)
    #pragma unroll
    for (int i = 0; i < MI; ++i) {
        #pragma unroll
        for (int j = 0; j < NJ; ++j) {
            int colg = bn * BN + wn * (BN / 2) + j * 16 + mrow;
            #pragma unroll
            for (int r = 0; r < 4; ++r) {
                int rowg = bm * BM + wm * (BM / 2) + i * 16 + quad * 4 + r;
                if (MODE == 0) {
                    ((u16*)Cv)[(size_t)rowg * ldc + colg] = f2bf(acc[i][j][r]);
                } else {
                    ((float*)Cv)[(size_t)rowg * ldc + colg] = acc[i][j][r] + bias[colg];
                }
            }
        }
    }
}

// ---------------------------------------------------------------------------
// Attention v3: one wave per (b, h, ti).  Two-phase, branch-free slot set.
// Valid neighbor offsets (causal nb<=t <=> (df,dh,dw) lex<= 0): 9x df=-1,
// 3x (0,-1,dw), (0,0,-1), (0,0,0)  => 14 window slots + BOS = 15 (+1 pad).
// Phase 1: lane = j*4+g; Q/K loads issue first, then all 15 V-row loads
//   (prefetch — vmcnt FIFO keeps them in flight under the softmax chain);
//   dot via packed bf16-pair converts (u<<16 / u&0xffff0000) into 4 split
//   accumulators; batched softmax: 2-shfl dot reduce, 4-shfl max, ONE exp,
//   4-shfl sum, pe normalized by rcp(l).
// Phase 2: lane = dim; 15x (readlane pj + fma) on prefetched V regs.
// ---------------------------------------------------------------------------
__global__ __launch_bounds__(256)
void attn_kernel(const u16* __restrict__ QKV, u16* __restrict__ O) {
    const int wid  = blockIdx.x * 4 + (threadIdx.x >> 6);
    const int lane = threadIdx.x & 63;
    const int bh = wid >> 12;            // 16
    const int ti = wid & 4095;           // 4096
    const int b = bh >> 3, h = bh & 7;
    const size_t baseQ = (size_t)b * T_TOK * NQKV;
    const size_t baseO = (size_t)b * T_TOK * DIM;

    if (ti == 0) {                        // output row 0 = bos_v
        O[baseO + h * 64 + lane] = QKV[baseQ + 1024 + h * 64 + lane];
        return;
    }
    const int t = ti - 1;                 // grid position, 0..4094
    const int f = t >> 10, hh = (t >> 5) & 31, ww = t & 31;

    // ---- per-lane slot decode (wave-uniform t; j varies per lane)
    const int j = lane >> 2, g = lane & 3;
    int jm1 = j - 1;
    int dh9 = ((jm1 * 11) >> 5) - 1;      // j in 1..9: (j-1)/3 - 1
    int dw9 = jm1 - (dh9 + 1) * 3 - 1;    // j in 1..9: (j-1)%3 - 1
    int df = (j >= 1 && j <= 9) ? -1 : 0;
    int dh = (j >= 1 && j <= 9) ? dh9 : ((j >= 10 && j <= 12) ? -1 : 0);
    int dw = (j >= 1 && j <= 9) ? dw9 :
             ((j >= 10 && j <= 12) ? (j - 11) : ((j == 13) ? -1 : 0));
    int nf = f + df, nh = hh + dh, nw = ww + dw;
    int valid = (nf >= 0) && ((unsigned)nh < 32u) && ((unsigned)nw < 32u)
                && (j >= 1) && (j <= 14);
    int p = valid ? (t + 1 + df * 1024 + dh * 32 + dw) : 0;   // j==0 -> BOS
    int score_on = valid || (j == 0);
    u32 voff = (u32)p * 3072u;            // byte offset of V row p

    // ---- issue Q/K loads (needed first), then prefetch 15 V rows
    const u32* qp = (const u32*)(QKV + baseQ + (size_t)(t + 1) * NQKV + h * 64 + g * 16);
    const u32* kp = (const u32*)(QKV + baseQ + (size_t)p * NQKV + 512 + h * 64 + g * 16);
    u32 qu[8], ku[8];
    #pragma unroll
    for (int i = 0; i < 8; ++i) { qu[i] = qp[i]; ku[i] = kp[i]; }

    const char* vb = (const char*)(QKV + baseQ + 1024 + h * 64 + lane);
    u32 vreg[15];
    #pragma unroll
    for (int jj = 0; jj < 15; ++jj) {
        u32 o = (u32)__builtin_amdgcn_readlane((int)voff, jj * 4);
        vreg[jj] = *(const u16*)(vb + o);            // zero-extending load
    }

    // ---- dot: packed bf16 pairs, 4 split accumulators
    float ax = 0.f, ay = 0.f, bx = 0.f, by = 0.f;
    #pragma unroll
    for (int i = 0; i < 8; i += 2) {
        ax = fmaf(bflo(qu[i]),     bflo(ku[i]),     ax);
        ay = fmaf(bfhi(qu[i]),     bfhi(ku[i]),     ay);
        bx = fmaf(bflo(qu[i + 1]), bflo(ku[i + 1]), bx);
        by = fmaf(bfhi(qu[i + 1]), bfhi(ku[i + 1]), by);
    }
    float s = (ax + ay) + (bx + by);
    s += __shfl_xor(s, 1);
    s += __shfl_xor(s, 2);                // all 4 g-lanes of slot j hold dot_j
    s *= 0.125f;                          // SCALE
    s = score_on ? s : -3.0e38f;

    float m = s;
    #pragma unroll
    for (int off = 4; off <= 32; off <<= 1) m = fmaxf(m, __shfl_xor(m, off));
    float pe = __expf(s - m);             // masked lanes -> 0
    float l = pe;
    #pragma unroll
    for (int off = 4; off <= 32; off <<= 1) l += __shfl_xor(l, off);
    float pen = pe * __frcp_rn(l);        // normalized weight, wave-wide

    // ---- phase 2: PV on prefetched V regs, lane = dim
    float acc = 0.f;
    #pragma unroll
    for (int jj = 0; jj < 15; ++jj) {
        float pj = __uint_as_float(
                     (u32)__builtin_amdgcn_readlane((int)__float_as_uint(pen), jj * 4));
        acc = fmaf(pj, __uint_as_float(vreg[jj] << 16), acc);
    }
    O[baseO + (size_t)ti * DIM + h * 64 + lane] = f2bf(acc);
}

// ---------------------------------------------------------------------------
// launch: cast -> gemm1 (QKV) -> attn -> gemm2 (out proj + bias)
// ws layout (bytes): xb 8M @0 | Wt 1.5M @8388608 | Wot 0.5M @9961472 |
//                    QKV 24M @10485760 | O aliases xb @0   (total ~34MB)
// ---------------------------------------------------------------------------
extern "C" void kernel_launch(void* const* d_in, const int* in_sizes, int n_in,
                              void* d_out, int out_size, void* d_ws, size_t ws_size,
                              hipStream_t stream) {
    const float* x   = (const float*)d_in[0];
    const float* Wq  = (const float*)d_in[1];
    const float* Wkv = (const float*)d_in[2];
    const float* Wo  = (const float*)d_in[3];
    const float* bo  = (const float*)d_in[4];
    float* out = (float*)d_out;
    char* ws = (char*)d_ws;

    u16* xb  = (u16*)(ws + 0);
    u16* Wt  = (u16*)(ws + 8388608);
    u16* Wot = (u16*)(ws + 9961472);
    u16* QKV = (u16*)(ws + 10485760);
    u16* O   = (u16*)(ws + 0);          // aliases xb (dead after gemm1)

    cast_all_kernel<<<dim3(4352), dim3(256), 0, stream>>>(
        (const float4*)x, Wq, Wkv, Wo, xb, Wt, Wot);
    gemm_nt<128, 128, 0><<<dim3(12, 64), dim3(256), 0, stream>>>(
        xb, Wt, (void*)QKV, nullptr, 512, 512, 1536);
    attn_kernel<<<dim3(16384), dim3(256), 0, stream>>>(QKV, O);
    gemm_nt<128, 64, 1><<<dim3(8, 64), dim3(256), 0, stream>>>(
        O, Wot, (void*)out, bo, 512, 512, 512);
}

// Round 8
// 139.294 us; speedup vs baseline: 1.0094x; 1.0094x over previous
//
#include <hip/hip_runtime.h>

// ---------------------------------------------------------------------------
// Sparse3DNA: x->QKV proj (bf16 MFMA GEMM), 3x3x3 causal window attention
// (+BOS), output proj. Shapes: b=2, T=4096 (4x32x32), DIM=512, 8 heads x 64.
// R8: 3-stage LDS ring in gemm_nt — wait vmcnt(2*NLD) so the waited stage
// was issued TWO steps earlier (~600+cyc slack > L2 latency). gemm2 retiled
// 64x64 -> 1024 blocks = 4/CU. attn reverted to R6 (v3 was neutral-worse).
// ---------------------------------------------------------------------------

#define T_TOK   4096
#define DIM     512
#define NQKV    1536

typedef unsigned short u16;
typedef unsigned int   u32;
typedef unsigned long long u64;
typedef __attribute__((ext_vector_type(8))) short short8;   // 8 bf16 (4 VGPR)
typedef __attribute__((ext_vector_type(4))) float f32x4;

__device__ __forceinline__ u16 f2bf(float f) {           // RNE float->bf16
    u32 u = __float_as_uint(f);
    return (u16)((u + 0x7fffu + ((u >> 16) & 1u)) >> 16);
}
__device__ __forceinline__ float b2f(u16 u) {
    return __uint_as_float(((u32)u) << 16);
}

__device__ __forceinline__ void gload_lds16(const void* g, void* l) {
    // async global->LDS, 16B/lane; LDS dest = wave-uniform base + lane*16
    __builtin_amdgcn_global_load_lds(
        (const __attribute__((address_space(1))) void*)g,
        (__attribute__((address_space(3))) void*)l, 16, 0, 0);
}

// ---------------------------------------------------------------------------
// merged cast kernel.
//  blocks [0,4096): x fp32 -> bf16 (vectorized)
//  blocks [4096,4288): Wt[n][k] = [Wq|Wk|Wv](k,n), LDS-tiled 64x64 transpose
//  blocks [4288,4352): Wot[n][k] = Wo[k][n], same
// ---------------------------------------------------------------------------
__global__ void cast_all_kernel(const float4* __restrict__ x,
                                const float* __restrict__ Wq, const float* __restrict__ Wkv,
                                const float* __restrict__ Wo,
                                u16* __restrict__ xb, u16* __restrict__ Wt,
                                u16* __restrict__ Wot) {
    __shared__ float S[64 * 65];
    int blk = blockIdx.x;
    int tid = threadIdx.x;
    if (blk < 4096) {
        int i = blk * 256 + tid;                  // 1,048,576 float4s
        float4 v = x[i];
        u64 pack = (u64)f2bf(v.x) | ((u64)f2bf(v.y) << 16) |
                   ((u64)f2bf(v.z) << 32) | ((u64)f2bf(v.w) << 48);
        ((u64*)xb)[i] = pack;
        return;
    }
    int isWo = blk >= 4288;
    int tIdx = isWo ? (blk - 4288) : (blk - 4096);
    int tn = tIdx >> 3, tk = tIdx & 7;            // n-tile, k-tile
    #pragma unroll
    for (int p = 0; p < 16; ++p) {                // stage, coalesced over n
        int kl = p * 4 + (tid >> 6), nl = tid & 63;
        int gk = tk * 64 + kl, gn = tn * 64 + nl;
        float v;
        if (isWo)            v = Wo[gk * 512 + gn];
        else if (gn < 512)   v = Wq[gk * 512 + gn];
        else                 v = Wkv[gk * 1024 + (gn - 512)];
        S[kl * 65 + nl] = v;
    }
    __syncthreads();
    u16* dst = isWo ? Wot : Wt;
    #pragma unroll
    for (int p = 0; p < 16; ++p) {                // write, coalesced over k
        int nl = p * 4 + (tid >> 6), kl = tid & 63;
        dst[(size_t)(tn * 64 + nl) * 512 + tk * 64 + kl] = f2bf(S[kl * 65 + nl]);
    }
}

// ---------------------------------------------------------------------------
// NT GEMM, 3-stage LDS ring: C(MxN) = A(MxK) * B(NxK)^T, K=512, bf16, fp32.
// BMxBN / block, 4 waves (2x2), wave tile (BM/2)x(BN/2), mfma 16x16x32, BK=32.
// LDS XOR-swizzle: slot(r,kc) = r*4 + ((kc + (r>>1)) & 3) -> ds_read_b128
// lands 2 lanes/bank (free, m136).
// Ring: at step ks issue stage ks+2 -> buf[(ks+2)%3]; s_waitcnt vmcnt(2*NLD)
// guarantees stage ks (issued 2 steps ago) complete while ks+1/ks+2 ride;
// s_barrier; ds_read+MFMA on buf[ks%3]; lgkmcnt(0); s_barrier (safe reuse:
// buf[(ks+2)%3] was last read at step ks-1, behind that end barrier).
// MODE 0: bf16 store. MODE 1: fp32 store + bias.
// ---------------------------------------------------------------------------
template <int BM, int BN, int MODE>
__global__ __launch_bounds__(256)
void gemm_nt(const u16* __restrict__ A, const u16* __restrict__ B,
             void* __restrict__ Cv, const float* __restrict__ bias,
             int lda, int ldb, int ldc) {
    constexpr int K = 512, BK = 32, KSTEPS = K / BK;
    constexpr int ACH = BM * 4;                  // A 16B-chunks per K-step
    constexpr int NCH = (BM + BN) * 4;
    constexpr int NLD = NCH / 256;               // chunks per thread per stage
    constexpr int ABYTES = BM * 64;
    constexpr int HALF = (BM + BN) * 64;         // one ring buffer
    constexpr int MI = BM / 32, NJ = BN / 32;
    __shared__ __align__(16) char lds[3 * HALF];
    const int tid  = threadIdx.x;
    const int lane = tid & 63, wave = tid >> 6;
    const int quad = lane >> 4, mrow = lane & 15;
    const int wm = wave >> 1, wn = wave & 1;
    const int bm = blockIdx.y, bn = blockIdx.x;

    const char* gptr[NLD];
    char*       lptr[NLD];
    #pragma unroll
    for (int it = 0; it < NLD; ++it) {
        int c   = it * 256 + tid;                // chunk id, lane-consecutive
        int inB = (c >= ACH);
        int a   = inB ? c - ACH : c;
        int r   = a >> 2;                        // tile row
        int kc  = ((a & 3) - (r >> 1)) & 3;      // inverse swizzle
        int row = (inB ? bn * BN : bm * BM) + r;
        const u16* base = inB ? B : A;
        int ld = inB ? ldb : lda;
        gptr[it] = (const char*)(base + (size_t)row * ld + kc * 8);
        lptr[it] = (char*)lds + (it * 256 + wave * 64) * 16;   // wave-uniform
    }
    const char* aLds[MI];
    const char* bLds[NJ];
    #pragma unroll
    for (int i = 0; i < MI; ++i) {
        int ra = wm * (BM / 2) + i * 16 + mrow;
        aLds[i] = lds + (ra * 4 + ((quad + (ra >> 1)) & 3)) * 16;
    }
    #pragma unroll
    for (int j = 0; j < NJ; ++j) {
        int rb = wn * (BN / 2) + j * 16 + mrow;
        bLds[j] = lds + ABYTES + (rb * 4 + ((quad + (rb >> 1)) & 3)) * 16;
    }

    f32x4 acc[MI][NJ] = {};
    #pragma unroll
    for (int it = 0; it < NLD; ++it)             // prologue: stage 0 -> buf 0
        gload_lds16(gptr[it], lptr[it]);
    #pragma unroll
    for (int it = 0; it < NLD; ++it)             // prologue: stage 1 -> buf 1
        gload_lds16(gptr[it] + 2 * BK, lptr[it] + HALF);

    #pragma unroll
    for (int ks = 0; ks < KSTEPS; ++ks) {
        const int cur = ks % 3;
        if (ks + 2 < KSTEPS) {                   // issue stage ks+2
            const int nxt = (ks + 2) % 3;
            #pragma unroll
            for (int it = 0; it < NLD; ++it)
                gload_lds16(gptr[it] + 2 * (ks + 2) * BK, lptr[it] + nxt * HALF);
            asm volatile("s_waitcnt vmcnt(%0)" :: "i"(2 * NLD) : "memory");
        } else if (ks + 1 < KSTEPS) {            // stage KSTEPS-1 still flying
            asm volatile("s_waitcnt vmcnt(%0)" :: "i"(NLD) : "memory");
        } else {
            asm volatile("s_waitcnt vmcnt(0)" ::: "memory");
        }
        asm volatile("s_barrier" ::: "memory");  // stage ks visible to all

        short8 af[MI], bf[NJ];
        #pragma unroll
        for (int i = 0; i < MI; ++i) af[i] = *(const short8*)(aLds[i] + cur * HALF);
        #pragma unroll
        for (int j = 0; j < NJ; ++j) bf[j] = *(const short8*)(bLds[j] + cur * HALF);
        #pragma unroll
        for (int i = 0; i < MI; ++i)
            #pragma unroll
            for (int j = 0; j < NJ; ++j)
                acc[i][j] = __builtin_amdgcn_mfma_f32_16x16x32_bf16(af[i], bf[j], acc[i][j], 0, 0, 0);
        asm volatile("s_waitcnt lgkmcnt(0)" ::: "memory");
        asm volatile("s_barrier" ::: "memory");  // all waves done reading buf
    }

    // epilogue: D row = quad*4 + reg, col = lane&15 (m89-verified layout)
    #pragma unroll
    for (int i = 0; i < MI; ++i) {
        #pragma unroll
        for (int j = 0; j < NJ; ++j) {
            int colg = bn * BN + wn * (BN / 2) + j * 16 + mrow;
            #pragma unroll
            for (int r = 0; r < 4; ++r) {
                int rowg = bm * BM + wm * (BM / 2) + i * 16 + quad * 4 + r;
                if (MODE == 0) {
                    ((u16*)Cv)[(size_t)rowg * ldc + colg] = f2bf(acc[i][j][r]);
                } else {
                    ((float*)Cv)[(size_t)rowg * ldc + colg] = acc[i][j][r] + bias[colg];
                }
            }
        }
    }
}

// ---------------------------------------------------------------------------
// Attention (R6 version): one wave per (b, h, ti).  Two-phase, branch-free.
// Valid neighbor offsets (causal nb<=t <=> (df,dh,dw) lex<= 0): 9x df=-1,
// 3x (0,-1,dw), (0,0,-1), (0,0,0)  => 14 window slots + BOS = 15 (+1 pad).
// Phase 1: lane = j*4+g; 16-dim partial dot, 2-shfl reduce, batched softmax
//   (4-shfl max, ONE exp, 4-shfl sum), pe normalized by rcp(l).
// Phase 2: lane = dim; 15x (2 readlane + u16 load + fma), u32 byte offsets.
// ---------------------------------------------------------------------------
__global__ __launch_bounds__(256)
void attn_kernel(const u16* __restrict__ QKV, u16* __restrict__ O) {
    const int wid  = blockIdx.x * 4 + (threadIdx.x >> 6);
    const int lane = threadIdx.x & 63;
    const int bh = wid >> 12;            // 16
    const int ti = wid & 4095;           // 4096
    const int b = bh >> 3, h = bh & 7;
    const size_t baseQ = (size_t)b * T_TOK * NQKV;
    const size_t baseO = (size_t)b * T_TOK * DIM;

    if (ti == 0) {                        // output row 0 = bos_v
        O[baseO + h * 64 + lane] = QKV[baseQ + 1024 + h * 64 + lane];
        return;
    }
    const int t = ti - 1;                 // grid position, 0..4094
    const int f = t >> 10, hh = (t >> 5) & 31, ww = t & 31;

    const int j = lane >> 2, g = lane & 3;
    int jm1 = j - 1;
    int dh9 = ((jm1 * 11) >> 5) - 1;      // j in 1..9: (j-1)/3 - 1
    int dw9 = jm1 - (dh9 + 1) * 3 - 1;    // j in 1..9: (j-1)%3 - 1
    int df = (j >= 1 && j <= 9) ? -1 : 0;
    int dh = (j >= 1 && j <= 9) ? dh9 : ((j >= 10 && j <= 12) ? -1 : 0);
    int dw = (j >= 1 && j <= 9) ? dw9 :
             ((j >= 10 && j <= 12) ? (j - 11) : ((j == 13) ? -1 : 0));
    int nf = f + df, nh = hh + dh, nw = ww + dw;
    int valid = (nf >= 0) && ((unsigned)nh < 32u) && ((unsigned)nw < 32u)
                && (j >= 1) && (j <= 14);
    int p = valid ? (t + 1 + df * 1024 + dh * 32 + dw) : 0;   // j==0 -> BOS
    int score_on = valid || (j == 0);

    // ---- phase 1: scores
    const u16* qrow = QKV + baseQ + (size_t)(t + 1) * NQKV + h * 64 + g * 16;
    short8 q0 = *(const short8*)qrow;
    short8 q1 = *(const short8*)(qrow + 8);
    const u16* krow = QKV + baseQ + (size_t)p * NQKV + 512 + h * 64 + g * 16;
    short8 k0 = *(const short8*)krow;
    short8 k1 = *(const short8*)(krow + 8);
    float s = 0.f;
    #pragma unroll
    for (int i = 0; i < 8; ++i) {
        s = fmaf(b2f((u16)q0[i]), b2f((u16)k0[i]), s);
        s = fmaf(b2f((u16)q1[i]), b2f((u16)k1[i]), s);
    }
    s += __shfl_xor(s, 1);
    s += __shfl_xor(s, 2);                // all 4 g-lanes of slot j hold dot_j
    s *= 0.125f;                          // SCALE
    s = score_on ? s : -3.0e38f;

    float m = s;
    #pragma unroll
    for (int off = 4; off <= 32; off <<= 1) m = fmaxf(m, __shfl_xor(m, off));
    float pe = __expf(s - m);             // masked lanes -> 0
    float l = pe;
    #pragma unroll
    for (int off = 4; off <= 32; off <<= 1) l += __shfl_xor(l, off);
    float pen = pe * __frcp_rn(l);        // normalized weight, wave-wide
    u32 voff = (u32)p * 3072u;            // byte offset of V row p

    // ---- phase 2: PV, lane = dim
    float acc = 0.f;
    const char* vb = (const char*)(QKV + baseQ + 1024 + h * 64 + lane);
    #pragma unroll
    for (int jj = 0; jj < 15; ++jj) {
        u32 o = (u32)__builtin_amdgcn_readlane((int)voff, jj * 4);
        float pj = __uint_as_float(
                     (u32)__builtin_amdgcn_readlane((int)__float_as_uint(pen), jj * 4));
        float vv = b2f(*(const u16*)(vb + o));
        acc = fmaf(pj, vv, acc);
    }
    O[baseO + (size_t)ti * DIM + h * 64 + lane] = f2bf(acc);
}

// ---------------------------------------------------------------------------
// launch: cast -> gemm1 (QKV) -> attn -> gemm2 (out proj + bias)
// ws layout (bytes): xb 8M @0 | Wt 1.5M @8388608 | Wot 0.5M @9961472 |
//                    QKV 24M @10485760 | O aliases xb @0   (total ~34MB)
// ---------------------------------------------------------------------------
extern "C" void kernel_launch(void* const* d_in, const int* in_sizes, int n_in,
                              void* d_out, int out_size, void* d_ws, size_t ws_size,
                              hipStream_t stream) {
    const float* x   = (const float*)d_in[0];
    const float* Wq  = (const float*)d_in[1];
    const float* Wkv = (const float*)d_in[2];
    const float* Wo  = (const float*)d_in[3];
    const float* bo  = (const float*)d_in[4];
    float* out = (float*)d_out;
    char* ws = (char*)d_ws;

    u16* xb  = (u16*)(ws + 0);
    u16* Wt  = (u16*)(ws + 8388608);
    u16* Wot = (u16*)(ws + 9961472);
    u16* QKV = (u16*)(ws + 10485760);
    u16* O   = (u16*)(ws + 0);          // aliases xb (dead after gemm1)

    cast_all_kernel<<<dim3(4352), dim3(256), 0, stream>>>(
        (const float4*)x, Wq, Wkv, Wo, xb, Wt, Wot);
    gemm_nt<128, 128, 0><<<dim3(12, 64), dim3(256), 0, stream>>>(
        xb, Wt, (void*)QKV, nullptr, 512, 512, 1536);
    attn_kernel<<<dim3(16384), dim3(256), 0, stream>>>(QKV, O);
    gemm_nt<64, 64, 1><<<dim3(8, 128), dim3(256), 0, stream>>>(
        O, Wot, (void*)out, bo, 512, 512, 512);
}

// Round 9
// 134.820 us; speedup vs baseline: 1.0429x; 1.0332x over previous
//
#include <hip/hip_runtime.h>

// ---------------------------------------------------------------------------
// Sparse3DNA: x->QKV proj (bf16 MFMA GEMM), 3x3x3 causal window attention
// (+BOS), output proj. Shapes: b=2, T=4096 (4x32x32), DIM=512, 8 heads x 64.
// R9: attn v4 — TWO heads (same token) per wave: slot decode shared, two
// independent K/dot/softmax/V chains interleave (2x memory-level parallelism
// for a latency-bound kernel); wave count 65536 -> 32768.
// GEMM = R6 dbuf structure (best measured total).
// ---------------------------------------------------------------------------

#define T_TOK   4096
#define DIM     512
#define NQKV    1536

typedef unsigned short u16;
typedef unsigned int   u32;
typedef unsigned long long u64;
typedef __attribute__((ext_vector_type(8))) short short8;   // 8 bf16 (4 VGPR)
typedef __attribute__((ext_vector_type(4))) float f32x4;

__device__ __forceinline__ u16 f2bf(float f) {           // RNE float->bf16
    u32 u = __float_as_uint(f);
    return (u16)((u + 0x7fffu + ((u >> 16) & 1u)) >> 16);
}
__device__ __forceinline__ float b2f(u16 u) {
    return __uint_as_float(((u32)u) << 16);
}

__device__ __forceinline__ void gload_lds16(const void* g, void* l) {
    // async global->LDS, 16B/lane; LDS dest = wave-uniform base + lane*16
    __builtin_amdgcn_global_load_lds(
        (const __attribute__((address_space(1))) void*)g,
        (__attribute__((address_space(3))) void*)l, 16, 0, 0);
}

// ---------------------------------------------------------------------------
// merged cast kernel.
//  blocks [0,4096): x fp32 -> bf16 (vectorized)
//  blocks [4096,4288): Wt[n][k] = [Wq|Wk|Wv](k,n), LDS-tiled 64x64 transpose
//  blocks [4288,4352): Wot[n][k] = Wo[k][n], same
// ---------------------------------------------------------------------------
__global__ void cast_all_kernel(const float4* __restrict__ x,
                                const float* __restrict__ Wq, const float* __restrict__ Wkv,
                                const float* __restrict__ Wo,
                                u16* __restrict__ xb, u16* __restrict__ Wt,
                                u16* __restrict__ Wot) {
    __shared__ float S[64 * 65];
    int blk = blockIdx.x;
    int tid = threadIdx.x;
    if (blk < 4096) {
        int i = blk * 256 + tid;                  // 1,048,576 float4s
        float4 v = x[i];
        u64 pack = (u64)f2bf(v.x) | ((u64)f2bf(v.y) << 16) |
                   ((u64)f2bf(v.z) << 32) | ((u64)f2bf(v.w) << 48);
        ((u64*)xb)[i] = pack;
        return;
    }
    int isWo = blk >= 4288;
    int tIdx = isWo ? (blk - 4288) : (blk - 4096);
    int tn = tIdx >> 3, tk = tIdx & 7;            // n-tile, k-tile
    #pragma unroll
    for (int p = 0; p < 16; ++p) {                // stage, coalesced over n
        int kl = p * 4 + (tid >> 6), nl = tid & 63;
        int gk = tk * 64 + kl, gn = tn * 64 + nl;
        float v;
        if (isWo)            v = Wo[gk * 512 + gn];
        else if (gn < 512)   v = Wq[gk * 512 + gn];
        else                 v = Wkv[gk * 1024 + (gn - 512)];
        S[kl * 65 + nl] = v;
    }
    __syncthreads();
    u16* dst = isWo ? Wot : Wt;
    #pragma unroll
    for (int p = 0; p < 16; ++p) {                // write, coalesced over k
        int nl = p * 4 + (tid >> 6), kl = tid & 63;
        dst[(size_t)(tn * 64 + nl) * 512 + tk * 64 + kl] = f2bf(S[kl * 65 + nl]);
    }
}

// ---------------------------------------------------------------------------
// NT GEMM, double-buffered: C(MxN) = A(MxK) * B(NxK)^T, K=512, bf16, fp32 acc.
// BMxBN / block, 4 waves (2x2), wave tile (BM/2)x(BN/2), mfma 16x16x32, BK=32.
// LDS XOR-swizzle: slot(r,kc) = r*4 + ((kc + (r>>1)) & 3) -> ds_read_b128
// lands 2 lanes/bank (free, m136).  K-loop per step:
//   stage(ks+1 -> buf^1); s_waitcnt vmcnt(NLD); s_barrier; frags+MFMA;
//   s_waitcnt lgkmcnt(0); s_barrier.
// MODE 0: bf16 store. MODE 1: fp32 store + bias.
// ---------------------------------------------------------------------------
template <int BM, int BN, int MODE>
__global__ __launch_bounds__(256)
void gemm_nt(const u16* __restrict__ A, const u16* __restrict__ B,
             void* __restrict__ Cv, const float* __restrict__ bias,
             int lda, int ldb, int ldc) {
    constexpr int K = 512, BK = 32, KSTEPS = K / BK;
    constexpr int ACH = BM * 4;                  // A 16B-chunks per K-step
    constexpr int NCH = (BM + BN) * 4;
    constexpr int NLD = NCH / 256;               // chunks per thread per stage
    constexpr int ABYTES = BM * 64;
    constexpr int HALF = (BM + BN) * 64;         // one buffer
    constexpr int MI = BM / 32, NJ = BN / 32;
    __shared__ __align__(16) char lds[2 * HALF];
    const int tid  = threadIdx.x;
    const int lane = tid & 63, wave = tid >> 6;
    const int quad = lane >> 4, mrow = lane & 15;
    const int wm = wave >> 1, wn = wave & 1;
    const int bm = blockIdx.y, bn = blockIdx.x;

    const char* gptr[NLD];
    char*       lptr[NLD];
    #pragma unroll
    for (int it = 0; it < NLD; ++it) {
        int c   = it * 256 + tid;                // chunk id, lane-consecutive
        int inB = (c >= ACH);
        int a   = inB ? c - ACH : c;
        int r   = a >> 2;                        // tile row
        int kc  = ((a & 3) - (r >> 1)) & 3;      // inverse swizzle
        int row = (inB ? bn * BN : bm * BM) + r;
        const u16* base = inB ? B : A;
        int ld = inB ? ldb : lda;
        gptr[it] = (const char*)(base + (size_t)row * ld + kc * 8);
        lptr[it] = (char*)lds + (it * 256 + wave * 64) * 16;   // wave-uniform
    }
    const char* aLds[MI];
    const char* bLds[NJ];
    #pragma unroll
    for (int i = 0; i < MI; ++i) {
        int ra = wm * (BM / 2) + i * 16 + mrow;
        aLds[i] = lds + (ra * 4 + ((quad + (ra >> 1)) & 3)) * 16;
    }
    #pragma unroll
    for (int j = 0; j < NJ; ++j) {
        int rb = wn * (BN / 2) + j * 16 + mrow;
        bLds[j] = lds + ABYTES + (rb * 4 + ((quad + (rb >> 1)) & 3)) * 16;
    }

    f32x4 acc[MI][NJ] = {};
    #pragma unroll
    for (int it = 0; it < NLD; ++it)             // prologue: stage 0 -> buf 0
        gload_lds16(gptr[it], lptr[it]);

    #pragma unroll
    for (int ks = 0; ks < KSTEPS; ++ks) {
        const int cur = ks & 1;
        if (ks + 1 < KSTEPS) {                   // prefetch next stage
            #pragma unroll
            for (int it = 0; it < NLD; ++it)
                gload_lds16(gptr[it] + 2 * (ks + 1) * BK, lptr[it] + (cur ^ 1) * HALF);
            asm volatile("s_waitcnt vmcnt(%0)" :: "i"(NLD) : "memory");
        } else {
            asm volatile("s_waitcnt vmcnt(0)" ::: "memory");
        }
        asm volatile("s_barrier" ::: "memory");  // stage ks visible to all

        short8 af[MI], bf[NJ];
        #pragma unroll
        for (int i = 0; i < MI; ++i) af[i] = *(const short8*)(aLds[i] + cur * HALF);
        #pragma unroll
        for (int j = 0; j < NJ; ++j) bf[j] = *(const short8*)(bLds[j] + cur * HALF);
        #pragma unroll
        for (int i = 0; i < MI; ++i)
            #pragma unroll
            for (int j = 0; j < NJ; ++j)
                acc[i][j] = __builtin_amdgcn_mfma_f32_16x16x32_bf16(af[i], bf[j], acc[i][j], 0, 0, 0);
        asm volatile("s_waitcnt lgkmcnt(0)" ::: "memory");
        asm volatile("s_barrier" ::: "memory");  // all waves done reading buf
    }

    // epilogue: D row = quad*4 + reg, col = lane&15 (m89-verified layout)
    #pragma unroll
    for (int i = 0; i < MI; ++i) {
        #pragma unroll
        for (int j = 0; j < NJ; ++j) {
            int colg = bn * BN + wn * (BN / 2) + j * 16 + mrow;
            #pragma unroll
            for (int r = 0; r < 4; ++r) {
                int rowg = bm * BM + wm * (BM / 2) + i * 16 + quad * 4 + r;
                if (MODE == 0) {
                    ((u16*)Cv)[(size_t)rowg * ldc + colg] = f2bf(acc[i][j][r]);
                } else {
                    ((float*)Cv)[(size_t)rowg * ldc + colg] = acc[i][j][r] + bias[colg];
                }
            }
        }
    }
}

// ---------------------------------------------------------------------------
// Attention v4: one wave per (b, head-PAIR, ti) — 32768 waves.
// Slot decode (p, valid, voff) is head-independent: computed once per wave.
// Two heads h0=2hp, h1=2hp+1 run as independent interleaved chains:
//   phase 1: 2x (Q,K loads; packed-dot; 2-shfl reduce); batched softmax per
//            head (4-shfl max, 1 exp, 4-shfl sum, rcp-normalize).
//   phase 2: shared readlane(voff); 2x (V load + readlane pj + fma).
// Doubles memory-level parallelism per wave (latency-bound kernel).
// ---------------------------------------------------------------------------
__global__ __launch_bounds__(256)
void attn_kernel(const u16* __restrict__ QKV, u16* __restrict__ O) {
    const int wid  = blockIdx.x * 4 + (threadIdx.x >> 6);   // 0..32767
    const int lane = threadIdx.x & 63;
    const int b  = wid >> 14;             // 2
    const int hp = (wid >> 12) & 3;       // head pair
    const int ti = wid & 4095;            // 4096
    const int h0 = hp * 2, h1 = h0 + 1;
    const size_t baseQ = (size_t)b * T_TOK * NQKV;
    const size_t baseO = (size_t)b * T_TOK * DIM;

    if (ti == 0) {                        // output row 0 = bos_v (both heads)
        O[baseO + h0 * 64 + lane] = QKV[baseQ + 1024 + h0 * 64 + lane];
        O[baseO + h1 * 64 + lane] = QKV[baseQ + 1024 + h1 * 64 + lane];
        return;
    }
    const int t = ti - 1;                 // grid position, 0..4094
    const int f = t >> 10, hh = (t >> 5) & 31, ww = t & 31;

    // ---- per-lane slot decode (wave-uniform t; j varies per lane) — shared
    const int j = lane >> 2, g = lane & 3;
    int jm1 = j - 1;
    int dh9 = ((jm1 * 11) >> 5) - 1;      // j in 1..9: (j-1)/3 - 1
    int dw9 = jm1 - (dh9 + 1) * 3 - 1;    // j in 1..9: (j-1)%3 - 1
    int df = (j >= 1 && j <= 9) ? -1 : 0;
    int dh = (j >= 1 && j <= 9) ? dh9 : ((j >= 10 && j <= 12) ? -1 : 0);
    int dw = (j >= 1 && j <= 9) ? dw9 :
             ((j >= 10 && j <= 12) ? (j - 11) : ((j == 13) ? -1 : 0));
    int nf = f + df, nh = hh + dh, nw = ww + dw;
    int valid = (nf >= 0) && ((unsigned)nh < 32u) && ((unsigned)nw < 32u)
                && (j >= 1) && (j <= 14);
    int p = valid ? (t + 1 + df * 1024 + dh * 32 + dw) : 0;   // j==0 -> BOS
    int score_on = valid || (j == 0);

    // ---- phase 1: scores, two heads interleaved
    const u16* qbase = QKV + baseQ + (size_t)(t + 1) * NQKV + g * 16;
    const u16* kbase = QKV + baseQ + (size_t)p * NQKV + 512 + g * 16;
    short8 q0a = *(const short8*)(qbase + h0 * 64);
    short8 q0b = *(const short8*)(qbase + h0 * 64 + 8);
    short8 q1a = *(const short8*)(qbase + h1 * 64);
    short8 q1b = *(const short8*)(qbase + h1 * 64 + 8);
    short8 k0a = *(const short8*)(kbase + h0 * 64);
    short8 k0b = *(const short8*)(kbase + h0 * 64 + 8);
    short8 k1a = *(const short8*)(kbase + h1 * 64);
    short8 k1b = *(const short8*)(kbase + h1 * 64 + 8);
    float s0 = 0.f, s1 = 0.f;
    #pragma unroll
    for (int i = 0; i < 8; ++i) {
        s0 = fmaf(b2f((u16)q0a[i]), b2f((u16)k0a[i]), s0);
        s1 = fmaf(b2f((u16)q1a[i]), b2f((u16)k1a[i]), s1);
        s0 = fmaf(b2f((u16)q0b[i]), b2f((u16)k0b[i]), s0);
        s1 = fmaf(b2f((u16)q1b[i]), b2f((u16)k1b[i]), s1);
    }
    s0 += __shfl_xor(s0, 1);  s1 += __shfl_xor(s1, 1);
    s0 += __shfl_xor(s0, 2);  s1 += __shfl_xor(s1, 2);
    s0 *= 0.125f;             s1 *= 0.125f;
    s0 = score_on ? s0 : -3.0e38f;
    s1 = score_on ? s1 : -3.0e38f;

    float m0 = s0, m1 = s1;
    #pragma unroll
    for (int off = 4; off <= 32; off <<= 1) {
        m0 = fmaxf(m0, __shfl_xor(m0, off));
        m1 = fmaxf(m1, __shfl_xor(m1, off));
    }
    float pe0 = __expf(s0 - m0), pe1 = __expf(s1 - m1);
    float l0 = pe0, l1 = pe1;
    #pragma unroll
    for (int off = 4; off <= 32; off <<= 1) {
        l0 += __shfl_xor(l0, off);
        l1 += __shfl_xor(l1, off);
    }
    float pen0 = pe0 * __frcp_rn(l0);     // normalized weights, wave-wide
    float pen1 = pe1 * __frcp_rn(l1);
    u32 voff = (u32)p * 3072u;            // byte offset of V row p (shared)

    // ---- phase 2: PV, lane = dim, two heads
    float acc0 = 0.f, acc1 = 0.f;
    const char* vb0 = (const char*)(QKV + baseQ + 1024 + h0 * 64 + lane);
    const char* vb1 = (const char*)(QKV + baseQ + 1024 + h1 * 64 + lane);
    #pragma unroll
    for (int jj = 0; jj < 15; ++jj) {
        u32 o = (u32)__builtin_amdgcn_readlane((int)voff, jj * 4);
        float pj0 = __uint_as_float(
                      (u32)__builtin_amdgcn_readlane((int)__float_as_uint(pen0), jj * 4));
        float pj1 = __uint_as_float(
                      (u32)__builtin_amdgcn_readlane((int)__float_as_uint(pen1), jj * 4));
        float v0 = b2f(*(const u16*)(vb0 + o));
        float v1 = b2f(*(const u16*)(vb1 + o));
        acc0 = fmaf(pj0, v0, acc0);
        acc1 = fmaf(pj1, v1, acc1);
    }
    O[baseO + (size_t)ti * DIM + h0 * 64 + lane] = f2bf(acc0);
    O[baseO + (size_t)ti * DIM + h1 * 64 + lane] = f2bf(acc1);
}

// ---------------------------------------------------------------------------
// launch: cast -> gemm1 (QKV) -> attn -> gemm2 (out proj + bias)
// ws layout (bytes): xb 8M @0 | Wt 1.5M @8388608 | Wot 0.5M @9961472 |
//                    QKV 24M @10485760 | O aliases xb @0   (total ~34MB)
// ---------------------------------------------------------------------------
extern "C" void kernel_launch(void* const* d_in, const int* in_sizes, int n_in,
                              void* d_out, int out_size, void* d_ws, size_t ws_size,
                              hipStream_t stream) {
    const float* x   = (const float*)d_in[0];
    const float* Wq  = (const float*)d_in[1];
    const float* Wkv = (const float*)d_in[2];
    const float* Wo  = (const float*)d_in[3];
    const float* bo  = (const float*)d_in[4];
    float* out = (float*)d_out;
    char* ws = (char*)d_ws;

    u16* xb  = (u16*)(ws + 0);
    u16* Wt  = (u16*)(ws + 8388608);
    u16* Wot = (u16*)(ws + 9961472);
    u16* QKV = (u16*)(ws + 10485760);
    u16* O   = (u16*)(ws + 0);          // aliases xb (dead after gemm1)

    cast_all_kernel<<<dim3(4352), dim3(256), 0, stream>>>(
        (const float4*)x, Wq, Wkv, Wo, xb, Wt, Wot);
    gemm_nt<128, 128, 0><<<dim3(12, 64), dim3(256), 0, stream>>>(
        xb, Wt, (void*)QKV, nullptr, 512, 512, 1536);
    attn_kernel<<<dim3(8192), dim3(256), 0, stream>>>(QKV, O);
    gemm_nt<128, 64, 1><<<dim3(8, 64), dim3(256), 0, stream>>>(
        O, Wot, (void*)out, bo, 512, 512, 512);
}